// Round 4
// baseline (324.009 us; speedup 1.0000x reference)
//
#include <hip/hip_runtime.h>

// Problem constants (reference: B=2, QL=2048, KVL=4096, HIDDEN=1024, NH=16, D=64)
#define HID   1024
#define NH    16
#define HD    64
#define QL    2048
#define KVL   4096
#define NB    2
// SCALE=0.125 and log2(e) folded into Wq at cast time; softmax uses exp2.
#define QSCALE 0.180336880111120426f

typedef short s8v  __attribute__((ext_vector_type(8)));  // 8 x bf16 bits (4 VGPRs)
typedef short s4v  __attribute__((ext_vector_type(4)));  // 4 x bf16 bits (b64)
typedef float f4v  __attribute__((ext_vector_type(4)));  // 16x16 MFMA accumulator
typedef float f16x __attribute__((ext_vector_type(16))); // 32x32 MFMA accumulator

__device__ __forceinline__ unsigned short f2bf(float f) {
  unsigned int u = __builtin_bit_cast(unsigned int, f);
  u += 0x7FFFu + ((u >> 16) & 1u);
  return (unsigned short)(u >> 16);
}
__device__ __forceinline__ float bf2f(unsigned short h) {
  unsigned int u = ((unsigned int)h) << 16;
  return __builtin_bit_cast(float, u);
}
__device__ __forceinline__ float fexp2(float x) {
#if __has_builtin(__builtin_amdgcn_exp2f)
  return __builtin_amdgcn_exp2f(x);
#else
  return exp2f(x);
#endif
}

// Pack two f32 -> one u32 of 2 bf16 (RNE), bit-explicit (low = first arg).
// Replaces v_cvt_pk_bf16_f32 inline asm: its S0->low/high order is the one
// semantic this pipeline never HW-verified (prime suspect for the ~1e-2
// even/odd-pair swap signature in rounds 2-3).
__device__ __forceinline__ unsigned packbf(float lo, float hi) {
  return (unsigned)f2bf(lo) | ((unsigned)f2bf(hi) << 16);
}

// Half-exchange across the lane<32 / lane>=32 split:
// After: x = {x[l] (l<32), y[l-32] (l>=32)}, y = {x[l+32] (l<32), y[l] (l>=32)}.
// shfl_xor-based (unambiguous semantics).
__device__ __forceinline__ void plswap(unsigned &x, unsigned &y) {
  unsigned sx = (unsigned)__shfl_xor((int)x, 32, 64);
  unsigned sy = (unsigned)__shfl_xor((int)y, 32, 64);
  unsigned nx = (threadIdx.x & 32) ? sy : x;
  unsigned ny = (threadIdx.x & 32) ? y : sx;
  x = nx;
  y = ny;
}

// ---------------------------------------------------------------------------
// cast_all: fp32 -> bf16 for all 7 tensors into one contiguous ws region.
// ---------------------------------------------------------------------------
__global__ __launch_bounds__(256)
void cast_all(const float* __restrict__ q, const float* __restrict__ k,
              const float* __restrict__ v, const float* __restrict__ wq,
              const float* __restrict__ wk, const float* __restrict__ wv,
              const float* __restrict__ wo, unsigned short* __restrict__ dst) {
  size_t c = (size_t)blockIdx.x * 256 + threadIdx.x;
  const float* src; size_t lc; float sc = 1.0f;
  if (c < 524288)       { src = q;  lc = c; }
  else if (c < 1572864) { src = k;  lc = c - 524288; }
  else if (c < 2621440) { src = v;  lc = c - 1572864; }
  else if (c < 2752512) { src = wq; lc = c - 2621440; sc = QSCALE; }
  else if (c < 2883584) { src = wk; lc = c - 2752512; }
  else if (c < 3014656) { src = wv; lc = c - 2883584; }
  else                  { src = wo; lc = c - 3014656; }
  const float4* p = (const float4*)(src + lc * 8);
  float4 a = p[0], b = p[1];
  union { s8v v8; unsigned short h[8]; } u;
  u.h[0] = f2bf(a.x * sc); u.h[1] = f2bf(a.y * sc);
  u.h[2] = f2bf(a.z * sc); u.h[3] = f2bf(a.w * sc);
  u.h[4] = f2bf(b.x * sc); u.h[5] = f2bf(b.y * sc);
  u.h[6] = f2bf(b.z * sc); u.h[7] = f2bf(b.w * sc);
  *(s8v*)(dst + c * 8) = u.v8;
}

// ---------------------------------------------------------------------------
// DMA helper
// ---------------------------------------------------------------------------
typedef const __attribute__((address_space(1))) unsigned int* gas_t;
typedef __attribute__((address_space(3))) unsigned int*       las_t;

__device__ __forceinline__ void gl_lds16(const unsigned short* g, unsigned short* l) {
  __builtin_amdgcn_global_load_lds((gas_t)(const void*)g, (las_t)(void*)l, 16, 0, 0);
}

// ---------------------------------------------------------------------------
// GEMM body, dbuf DMA staging. Per-iter barrier drains vmcnt(0) (structural);
// mitigation = 4 blocks/CU so 4 barrier-groups overlap their drains.
// ---------------------------------------------------------------------------
template <bool OUT_BF16>
__device__ __forceinline__ void gemm_body(const unsigned short* __restrict__ A,
                                          const unsigned short* __restrict__ B,
                                          void* __restrict__ Cv, int N, int K,
                                          int bx, int by,
                                          unsigned short (*As)[128 * 32],
                                          unsigned short (*Bs)[128 * 32]) {
  const int tid  = threadIdx.x;
  const int wave = tid >> 6, lane = tid & 63;
  const int wm = wave >> 1, wn = wave & 1;
  const int quad = lane >> 4, l15 = lane & 15;
  const int row0 = by * 128;
  const int col0 = bx * 128;
  const int srow = lane >> 2;
  const int scol = (lane & 3) * 8;

  f4v acc[4][4] = {};

#define G_STAGE(KI, BI)                                                         \
  {                                                                             \
    _Pragma("unroll")                                                           \
    for (int cc = 0; cc < 2; cc++) {                                            \
      int c = wave + cc * 4;                                                    \
      gl_lds16(A + (size_t)(row0 + c * 16 + srow) * K + (KI) * 32 + scol,       \
               &As[BI][c * 512]);                                               \
      gl_lds16(B + (size_t)(col0 + c * 16 + srow) * K + (KI) * 32 + scol,       \
               &Bs[BI][c * 512]);                                               \
    }                                                                           \
  }

  const int nk = K >> 5;
  G_STAGE(0, 0);
  __syncthreads();

  for (int ki = 0; ki < nk; ki++) {
    const int cur = ki & 1;
    if (ki + 1 < nk) G_STAGE(ki + 1, 1 - cur);

    s8v af[4], bf[4];
#pragma unroll
    for (int i = 0; i < 4; i++)
      af[i] = *(const s8v*)&As[cur][(wm * 64 + i * 16 + l15) * 32 + quad * 8];
#pragma unroll
    for (int j = 0; j < 4; j++)
      bf[j] = *(const s8v*)&Bs[cur][(wn * 64 + j * 16 + l15) * 32 + quad * 8];
#pragma unroll
    for (int i = 0; i < 4; i++)
#pragma unroll
      for (int j = 0; j < 4; j++)
        acc[i][j] = __builtin_amdgcn_mfma_f32_16x16x32_bf16(af[i], bf[j],
                                                            acc[i][j], 0, 0, 0);
    __syncthreads();
  }
#undef G_STAGE

#pragma unroll
  for (int i = 0; i < 4; i++) {
#pragma unroll
    for (int j = 0; j < 4; j++) {
      int r = row0 + wm * 64 + i * 16 + quad * 4;
      int c = col0 + wn * 64 + j * 16 + l15;
#pragma unroll
      for (int reg = 0; reg < 4; reg++) {
        float v = acc[i][j][reg];
        if constexpr (OUT_BF16)
          ((unsigned short*)Cv)[(size_t)(r + reg) * N + c] = f2bf(v);
        else
          ((float*)Cv)[(size_t)(r + reg) * N + c] = v;
      }
    }
  }
}

// Q + K + V projections in ONE dispatch (1280 blocks, all 128x128 tiles).
__global__ __launch_bounds__(256, 4)
void proj_fused(const unsigned short* __restrict__ qc, const unsigned short* __restrict__ kc,
                const unsigned short* __restrict__ vc, const unsigned short* __restrict__ wqc,
                const unsigned short* __restrict__ wkc, const unsigned short* __restrict__ wvc,
                unsigned short* __restrict__ qp, unsigned short* __restrict__ kp,
                unsigned short* __restrict__ vpt) {
  __shared__ unsigned short As[2][128 * 32];
  __shared__ unsigned short Bs[2][128 * 32];
  int bid = blockIdx.x;
  if (bid < 256) {
    gemm_body<true>(qc, wqc, qp, HID, HID, bid & 7, bid >> 3, As, Bs);
  } else if (bid < 768) {
    int l = bid - 256;
    gemm_body<true>(kc, wkc, kp, HID, HID, l & 7, l >> 3, As, Bs);
  } else {
    int l = bid - 768;
    int b = l >> 8, r = l & 255;
    gemm_body<true>(wvc, vc + (size_t)b * KVL * HID,
                    vpt + (size_t)b * HID * KVL, KVL, HID, r & 31, r >> 5, As, Bs);
  }
}

__global__ __launch_bounds__(256, 4)
void o_gemm(const unsigned short* __restrict__ ao, const unsigned short* __restrict__ woc,
            float* __restrict__ out) {
  __shared__ unsigned short As[2][128 * 32];
  __shared__ unsigned short Bs[2][128 * 32];
  int bid = blockIdx.x;
  gemm_body<false>(ao, woc, out, HID, HID, bid & 7, bid >> 3, As, Bs);
}

// ---------------------------------------------------------------------------
// gemm_conv (fallback for small ws): convert-on-stage GEMM, padded LDS.
// ---------------------------------------------------------------------------
#define LDSK 40

template <typename T>
__device__ __forceinline__ void stage_tile(unsigned short* dst, const T* src,
                                           int ld, int tid, float sc) {
#pragma unroll
  for (int rep = 0; rep < 2; rep++) {
    int s = rep * 256 + tid;
    int row = s >> 2;
    int cs  = (s & 3) * 8;
    const T* p = src + (size_t)row * ld + cs;
    s8v val;
    if constexpr (sizeof(T) == 4) {
      float4 f0 = *(const float4*)p;
      float4 f1 = *(const float4*)(p + 4);
      union { s8v v; unsigned short h[8]; } u;
      u.h[0] = f2bf(f0.x * sc); u.h[1] = f2bf(f0.y * sc);
      u.h[2] = f2bf(f0.z * sc); u.h[3] = f2bf(f0.w * sc);
      u.h[4] = f2bf(f1.x * sc); u.h[5] = f2bf(f1.y * sc);
      u.h[6] = f2bf(f1.z * sc); u.h[7] = f2bf(f1.w * sc);
      val = u.v;
    } else {
      val = *(const s8v*)p;
    }
    *(s8v*)&dst[row * LDSK + cs] = val;
  }
}

template <typename TA, typename TB, bool OUT_BF16>
__global__ __launch_bounds__(256)
void gemm_conv(const TA* __restrict__ A, const TB* __restrict__ B,
               void* __restrict__ Cv, int M, int N, int K, float bscale,
               long long bz, long long cz) {
  __shared__ unsigned short As[128 * LDSK];
  __shared__ unsigned short Bs[128 * LDSK];
  const TB* Bp = B + (size_t)blockIdx.z * (size_t)bz;
  const int tid  = threadIdx.x;
  const int wave = tid >> 6, lane = tid & 63;
  const int wm = wave >> 1, wn = wave & 1;
  const int quad = lane >> 4, l15 = lane & 15;
  const int row0 = blockIdx.y * 128;
  const int col0 = blockIdx.x * 128;

  f4v acc[4][4] = {};

  for (int k0 = 0; k0 < K; k0 += 32) {
    __syncthreads();
    stage_tile(As, A + (size_t)row0 * K + k0, K, tid, 1.0f);
    stage_tile(Bs, Bp + (size_t)col0 * K + k0, K, tid, bscale);
    __syncthreads();

    s8v af[4], bf[4];
#pragma unroll
    for (int i = 0; i < 4; i++)
      af[i] = *(const s8v*)&As[(wm * 64 + i * 16 + l15) * LDSK + quad * 8];
#pragma unroll
    for (int j = 0; j < 4; j++)
      bf[j] = *(const s8v*)&Bs[(wn * 64 + j * 16 + l15) * LDSK + quad * 8];
#pragma unroll
    for (int i = 0; i < 4; i++)
#pragma unroll
      for (int j = 0; j < 4; j++)
        acc[i][j] = __builtin_amdgcn_mfma_f32_16x16x32_bf16(af[i], bf[j],
                                                            acc[i][j], 0, 0, 0);
  }

  char* Cp = (char*)Cv + (size_t)blockIdx.z * (size_t)cz * (OUT_BF16 ? 2 : 4);
#pragma unroll
  for (int i = 0; i < 4; i++) {
#pragma unroll
    for (int j = 0; j < 4; j++) {
      int r = row0 + wm * 64 + i * 16 + quad * 4;
      int c = col0 + wn * 64 + j * 16 + l15;
#pragma unroll
      for (int reg = 0; reg < 4; reg++) {
        float v = acc[i][j][reg];
        if constexpr (OUT_BF16)
          ((unsigned short*)Cp)[(size_t)(r + reg) * N + c] = f2bf(v);
        else
          ((float*)Cp)[(size_t)(r + reg) * N + c] = v;
      }
    }
  }
}

// ---------------------------------------------------------------------------
// attn8: S^T flash attention, 32x32 MFMA, zero-LDS softmax (in-reg repack),
//  proven attn6-style dbuf sync (__syncthreads per tile).
//  P packing now via bit-explicit f2bf (NO v_cvt_pk asm: its half-order was
//  the one unverified semantic; a swapped order produces exactly the ~1e-2
//  even/odd-pair-swap error signature observed in rounds 2-3).
//  LDS = 2*8K(K) + 2*8K(V) = 32 KB.
// ---------------------------------------------------------------------------
template <bool SPLIT>
__global__ __launch_bounds__(256, 2)
void attn8(const unsigned short* __restrict__ qp,
           const unsigned short* __restrict__ kp,
           const unsigned short* __restrict__ vpt,
           unsigned short* __restrict__ po,   // SPLIT: bf16 [2][NB*QL][HID]
           float* __restrict__ pl,            // SPLIT: f32 [2][NB*NH][QL]
           unsigned short* __restrict__ ao) { // !SPLIT: bf16 [NB*QL][HID]
  __shared__ unsigned short Ks[2][64 * 64];
  __shared__ unsigned short Vt[2][64 * 64];

  const int bid  = blockIdx.x;
  const int qb   = bid & 7;            // QL/256 = 8 q-blocks
  const int h    = (bid >> 3) & 15;
  const int b    = (bid >> 7) & 1;
  const int half = SPLIT ? (bid >> 8) : 0;
  const int tid  = threadIdx.x;
  const int wave = tid >> 6, lane = tid & 63;
  const int l31  = lane & 31, hi = lane >> 5;
  const int q0   = qb * 256 + wave * 64;
  const int kvoff = half * (KVL / 2);
  const int NT   = SPLIT ? (KVL / 128) : (KVL / 64);

  const unsigned short* kbase = kp + (size_t)b * KVL * HID + h * HD + (size_t)kvoff * HID;
  const unsigned short* vbase = vpt + (size_t)(b * NH + h) * HD * KVL + kvoff;

  // DMA staging coords: instr i in {0,1}: LDS chunk p = (i*4+wave)*64 + lane.
  // Global source column pre-swizzled so linear-LDS chunk j of row r holds
  // global chunk j^(r&7); reads use xc = (c ^ (r&7)).
  int prow[2], pcol[2], pbase[2];
#pragma unroll
  for (int i = 0; i < 2; i++) {
    int p = (i * 4 + wave) * 64 + lane;
    prow[i]  = p >> 3;
    pcol[i]  = ((p & 7) ^ (prow[i] & 7)) * 8;
    pbase[i] = (i * 4 + wave) * 512;
  }

  // Q fragments: B-operand of S^T (col=q=nt*32+l31, k=d=ks*16+hi*8+j)
  s8v qf[2][4];
#pragma unroll
  for (int nt = 0; nt < 2; nt++) {
    const unsigned short* qrow = qp + (size_t)(b * QL + q0 + nt * 32 + l31) * HID + h * HD;
#pragma unroll
    for (int ks = 0; ks < 4; ks++)
      qf[nt][ks] = *(const s8v*)(qrow + ks * 16 + hi * 8);
  }

  float lrun[2] = {0.f, 0.f};
  f16x oacc[2][2] = {};   // [nt][dt]: col=d=dt*32+l31, row=q=(r&3)+8*(r>>2)+4*hi

#define STAGE_KV(KT, BI)                                                        \
  {                                                                             \
    const unsigned short* kb = kbase + (size_t)((KT) * 64) * HID;               \
    const unsigned short* vb = vbase + (KT) * 64;                               \
    _Pragma("unroll")                                                           \
    for (int i = 0; i < 2; i++) {                                               \
      gl_lds16(kb + (size_t)prow[i] * HID + pcol[i], &Ks[BI][pbase[i]]);        \
      gl_lds16(vb + (size_t)prow[i] * KVL + pcol[i], &Vt[BI][pbase[i]]);        \
    }                                                                           \
  }

  STAGE_KV(0, 0);
  __syncthreads();

  for (int kt = 0; kt < NT; kt++) {
    const int cur = kt & 1;
    if (kt + 1 < NT) STAGE_KV(kt + 1, 1 - cur);

    // ---- S^T = K.Q^T (A = K-frag: row=kv, B = Q-frag: col=q) ----
    f16x sacc[2][2] = {};   // [mt][nt]
    __builtin_amdgcn_s_setprio(1);
#pragma unroll
    for (int ks = 0; ks < 4; ks++)
#pragma unroll
      for (int mt = 0; mt < 2; mt++) {
        int row = mt * 32 + l31;
        int xc  = ((ks * 2 + hi) ^ (row & 7)) * 8;
        s8v kf = *(const s8v*)&Ks[cur][row * 64 + xc];
#pragma unroll
        for (int nt = 0; nt < 2; nt++)
          sacc[mt][nt] = __builtin_amdgcn_mfma_f32_32x32x16_bf16(kf, qf[nt][ks],
                                                                 sacc[mt][nt], 0, 0, 0);
      }
    __builtin_amdgcn_s_setprio(0);

    // ---- softmax (exp2-domain, fixed shift) + in-register P repack ----
    // Lane holds P[q=nt*32+l31][kv = mt*32 + (r&3)+8*(r>>2)+4*hi].
    // PV A-frag: elem j of lane (l31,hi) must hold kv = (slot)*16 + hi*8 + j,
    // matching vf's load convention. Bit-explicit pack + half-swap via shfl.
    s8v paf[2][4];          // [nt][ks] A-fragments for PV
#pragma unroll
    for (int nt = 0; nt < 2; nt++) {
      float rs = 0.f;
#pragma unroll
      for (int mt = 0; mt < 2; mt++) {
        float e[16];
#pragma unroll
        for (int r = 0; r < 16; r++) e[r] = fexp2(sacc[mt][nt][r]);
        rs += ((((e[0] + e[1]) + (e[2] + e[3])) + ((e[4] + e[5]) + (e[6] + e[7])))
             + (((e[8] + e[9]) + (e[10] + e[11])) + ((e[12] + e[13]) + (e[14] + e[15]))));
        unsigned w0 = packbf(e[0],  e[1]);
        unsigned w1 = packbf(e[2],  e[3]);
        unsigned w2 = packbf(e[4],  e[5]);
        unsigned w3 = packbf(e[6],  e[7]);
        unsigned w4 = packbf(e[8],  e[9]);
        unsigned w5 = packbf(e[10], e[11]);
        unsigned w6 = packbf(e[12], e[13]);
        unsigned w7 = packbf(e[14], e[15]);
        plswap(w0, w2);   // -> frag ks=2mt   word0, word2
        plswap(w1, w3);   // -> frag ks=2mt   word1, word3
        plswap(w4, w6);   // -> frag ks=2mt+1 word0, word2
        plswap(w5, w7);   // -> frag ks=2mt+1 word1, word3
        union { unsigned w[4]; s8v v; } u0, u1;
        u0.w[0] = w0; u0.w[1] = w1; u0.w[2] = w2; u0.w[3] = w3;
        u1.w[0] = w4; u1.w[1] = w5; u1.w[2] = w6; u1.w[3] = w7;
        paf[nt][2 * mt]     = u0.v;
        paf[nt][2 * mt + 1] = u1.v;
      }
      rs += __shfl_xor(rs, 32, 64);
      lrun[nt] += rs;
    }

    // ---- O += P.V (A = P-frag in regs, B = V^T-frag: col=d) ----
    __builtin_amdgcn_s_setprio(1);
#pragma unroll
    for (int ks = 0; ks < 4; ks++)
#pragma unroll
      for (int dt = 0; dt < 2; dt++) {
        int row = dt * 32 + l31;
        int xc  = ((ks * 2 + hi) ^ (row & 7)) * 8;
        s8v vf = *(const s8v*)&Vt[cur][row * 64 + xc];
#pragma unroll
        for (int nt = 0; nt < 2; nt++)
          oacc[nt][dt] = __builtin_amdgcn_mfma_f32_32x32x16_bf16(paf[nt][ks], vf,
                                                                 oacc[nt][dt], 0, 0, 0);
      }
    __builtin_amdgcn_s_setprio(0);

    __syncthreads();
  }
#undef STAGE_KV

  if constexpr (SPLIT) {
    // unnormalized partials: O (bf16) + l (f32)
    unsigned short* pob = po + (size_t)half * NB * QL * HID;
#pragma unroll
    for (int nt = 0; nt < 2; nt++) {
#pragma unroll
      for (int dt = 0; dt < 2; dt++)
#pragma unroll
        for (int r = 0; r < 16; r++) {
          int qq = q0 + nt * 32 + (r & 3) + 8 * (r >> 2) + 4 * hi;
          int cc = h * HD + dt * 32 + l31;
          pob[(size_t)(b * QL + qq) * HID + cc] = f2bf(oacc[nt][dt][r]);
        }
      if (hi == 0)
        pl[(size_t)half * NB * NH * QL + (b * NH + h) * QL + q0 + nt * 32 + l31] = lrun[nt];
    }
  } else {
#pragma unroll
    for (int nt = 0; nt < 2; nt++) {
      float li = 1.0f / lrun[nt];
#pragma unroll
      for (int dt = 0; dt < 2; dt++)
#pragma unroll
        for (int r = 0; r < 16; r++) {
          int rr = (r & 3) + 8 * (r >> 2) + 4 * hi;
          float lv = __shfl(li, rr, 64);   // lane rr holds 1/l for q=nt*32+rr
          int qq = q0 + nt * 32 + rr;
          int cc = h * HD + dt * 32 + l31;
          ao[(size_t)(b * QL + qq) * HID + cc] = f2bf(oacc[nt][dt][r] * lv);
        }
    }
  }
}

// combine: ao = (po0 + po1) / (l0 + l1).  524288 threads, 8 elems each.
__global__ __launch_bounds__(256)
void combine(const unsigned short* __restrict__ po, const float* __restrict__ pl,
             unsigned short* __restrict__ ao) {
  int t  = blockIdx.x * 256 + threadIdx.x;
  int r  = t >> 7;           // row 0..4095 (b*QL+q)
  int c8 = t & 127;          // 8-col chunk; head h = c8>>3
  int b = r >> 11, q = r & 2047, h = c8 >> 3;
  size_t lidx = (size_t)(b * NH + h) * QL + q;
  float l = pl[lidx] + pl[(size_t)NB * NH * QL + lidx];
  float inv = 1.0f / l;
  size_t off = (size_t)r * HID + c8 * 8;
  s8v a = *(const s8v*)(po + off);
  s8v c = *(const s8v*)(po + (size_t)NB * QL * HID + off);
  union { s8v v8; unsigned short hh[8]; } ua, uc, uo;
  ua.v8 = a; uc.v8 = c;
#pragma unroll
  for (int e = 0; e < 8; e++)
    uo.hh[e] = f2bf((bf2f(ua.hh[e]) + bf2f(uc.hh[e])) * inv);
  *(s8v*)(ao + off) = uo.v8;
}

// ---------------------------------------------------------------------------
// Launch. Primary (ws >= 88 MiB):
//   @0 qc(8)->ao | @8 kc+vc(32)->po | @40 wqc(2)->pl | @42 wkc @44 wvc
//   @46 woc | @48 qp(8) | @56 kp(16) | @72 vpt(16)
// Fallback (48 MiB): gemm_conv chain + attn8<false> direct.
// ---------------------------------------------------------------------------
extern "C" void kernel_launch(void* const* d_in, const int* in_sizes, int n_in,
                              void* d_out, int out_size, void* d_ws, size_t ws_size,
                              hipStream_t stream) {
  const float* q  = (const float*)d_in[0];
  const float* k  = (const float*)d_in[1];
  const float* v  = (const float*)d_in[2];
  const float* Wq = (const float*)d_in[3];
  const float* Wk = (const float*)d_in[4];
  const float* Wv = (const float*)d_in[5];
  const float* Wo = (const float*)d_in[6];
  float* out = (float*)d_out;
  char* ws = (char*)d_ws;
  dim3 blk(256);

  const long long MB = 1024 * 1024;
  if (ws_size >= (size_t)88 * MB) {
    unsigned short* qc  = (unsigned short*)(ws);
    unsigned short* kc  = (unsigned short*)(ws + 8 * MB);
    unsigned short* vc  = (unsigned short*)(ws + 24 * MB);
    unsigned short* wqc = (unsigned short*)(ws + 40 * MB);
    unsigned short* wkc = (unsigned short*)(ws + 42 * MB);
    unsigned short* wvc = (unsigned short*)(ws + 44 * MB);
    unsigned short* woc = (unsigned short*)(ws + 46 * MB);
    unsigned short* qp  = (unsigned short*)(ws + 48 * MB);
    unsigned short* kp  = (unsigned short*)(ws + 56 * MB);
    unsigned short* vpt = (unsigned short*)(ws + 72 * MB);
    unsigned short* ao  = (unsigned short*)(ws);            // aliases qc (dead after proj)
    unsigned short* po  = (unsigned short*)(ws + 8 * MB);   // aliases kc/vc (dead after proj)
    float*          pl  = (float*)(ws + 40 * MB);           // aliases wqc (dead after proj)

    cast_all<<<12288, blk, 0, stream>>>(q, k, v, Wq, Wk, Wv, Wo, (unsigned short*)ws);
    proj_fused<<<1280, blk, 0, stream>>>(qc, kc, vc, wqc, wkc, wvc, qp, kp, vpt);
    attn8<true><<<512, blk, 0, stream>>>(qp, kp, vpt, po, pl, nullptr);
    combine<<<2048, blk, 0, stream>>>(po, pl, ao);
    o_gemm<<<256, blk, 0, stream>>>(ao, woc, out);
  } else {
    unsigned short* qp  = (unsigned short*)(ws);
    unsigned short* kp  = (unsigned short*)(ws + 8 * MB);
    unsigned short* vpt = (unsigned short*)(ws + 24 * MB);
    unsigned short* ao  = (unsigned short*)(ws + 40 * MB);

    gemm_conv<float, float, true><<<dim3(8, 32), blk, 0, stream>>>(q, Wq, qp, NB * QL, HID, HID, QSCALE, 0, 0);
    gemm_conv<float, float, true><<<dim3(8, 64), blk, 0, stream>>>(k, Wk, kp, NB * KVL, HID, HID, 1.0f, 0, 0);
    gemm_conv<float, float, true><<<dim3(32, 8, 2), blk, 0, stream>>>(Wv, v, vpt, HID, KVL, HID, 1.0f,
                                                                      (long long)KVL * HID, (long long)HID * KVL);
    attn8<false><<<256, blk, 0, stream>>>(qp, kp, vpt, nullptr, nullptr, ao);
    gemm_conv<unsigned short, float, false><<<dim3(8, 32), blk, 0, stream>>>(ao, Wo, out, NB * QL, HID, HID, 1.0f, 0, 0);
  }
}

// Round 5
// 308.173 us; speedup vs baseline: 1.0514x; 1.0514x over previous
//
#include <hip/hip_runtime.h>

// Problem constants (reference: B=2, QL=2048, KVL=4096, HIDDEN=1024, NH=16, D=64)
#define HID   1024
#define NH    16
#define HD    64
#define QL    2048
#define KVL   4096
#define NB    2
// SCALE=0.125 and log2(e) folded into Wq at cast time; softmax uses exp2.
#define QSCALE 0.180336880111120426f

typedef short s8v  __attribute__((ext_vector_type(8)));  // 8 x bf16 bits (4 VGPRs)
typedef short s4v  __attribute__((ext_vector_type(4)));  // 4 x bf16 bits (b64)
typedef float f4v  __attribute__((ext_vector_type(4)));  // 16x16 MFMA accumulator
typedef float f16x __attribute__((ext_vector_type(16))); // 32x32 MFMA accumulator

__device__ __forceinline__ unsigned short f2bf(float f) {
  unsigned int u = __builtin_bit_cast(unsigned int, f);
  u += 0x7FFFu + ((u >> 16) & 1u);
  return (unsigned short)(u >> 16);
}
__device__ __forceinline__ float bf2f(unsigned short h) {
  unsigned int u = ((unsigned int)h) << 16;
  return __builtin_bit_cast(float, u);
}
__device__ __forceinline__ float fexp2(float x) {
#if __has_builtin(__builtin_amdgcn_exp2f)
  return __builtin_amdgcn_exp2f(x);
#else
  return exp2f(x);
#endif
}

// Pack two f32 -> one u32 of 2 bf16 (RNE), bit-explicit (low = first arg).
// HW-verified in r4 (v_cvt_pk_bf16_f32 asm had swapped half-order; this passed).
__device__ __forceinline__ unsigned packbf(float lo, float hi) {
  return (unsigned)f2bf(lo) | ((unsigned)f2bf(hi) << 16);
}

// ---------------------------------------------------------------------------
// cast_all: fp32 -> bf16 for all 7 tensors into one contiguous ws region.
// ---------------------------------------------------------------------------
__global__ __launch_bounds__(256)
void cast_all(const float* __restrict__ q, const float* __restrict__ k,
              const float* __restrict__ v, const float* __restrict__ wq,
              const float* __restrict__ wk, const float* __restrict__ wv,
              const float* __restrict__ wo, unsigned short* __restrict__ dst) {
  size_t c = (size_t)blockIdx.x * 256 + threadIdx.x;
  const float* src; size_t lc; float sc = 1.0f;
  if (c < 524288)       { src = q;  lc = c; }
  else if (c < 1572864) { src = k;  lc = c - 524288; }
  else if (c < 2621440) { src = v;  lc = c - 1572864; }
  else if (c < 2752512) { src = wq; lc = c - 2621440; sc = QSCALE; }
  else if (c < 2883584) { src = wk; lc = c - 2752512; }
  else if (c < 3014656) { src = wv; lc = c - 2883584; }
  else                  { src = wo; lc = c - 3014656; }
  const float4* p = (const float4*)(src + lc * 8);
  float4 a = p[0], b = p[1];
  union { s8v v8; unsigned short h[8]; } u;
  u.h[0] = f2bf(a.x * sc); u.h[1] = f2bf(a.y * sc);
  u.h[2] = f2bf(a.z * sc); u.h[3] = f2bf(a.w * sc);
  u.h[4] = f2bf(b.x * sc); u.h[5] = f2bf(b.y * sc);
  u.h[6] = f2bf(b.z * sc); u.h[7] = f2bf(b.w * sc);
  *(s8v*)(dst + c * 8) = u.v8;
}

// ---------------------------------------------------------------------------
// DMA helper
// ---------------------------------------------------------------------------
typedef const __attribute__((address_space(1))) unsigned int* gas_t;
typedef __attribute__((address_space(3))) unsigned int*       las_t;

__device__ __forceinline__ void gl_lds16(const unsigned short* g, unsigned short* l) {
  __builtin_amdgcn_global_load_lds((gas_t)(const void*)g, (las_t)(void*)l, 16, 0, 0);
}

// ---------------------------------------------------------------------------
// GEMM body, dbuf DMA staging. Per-iter barrier drains vmcnt(0) (structural);
// mitigation = 4 blocks/CU so 4 barrier-groups overlap their drains.
// ---------------------------------------------------------------------------
template <bool OUT_BF16>
__device__ __forceinline__ void gemm_body(const unsigned short* __restrict__ A,
                                          const unsigned short* __restrict__ B,
                                          void* __restrict__ Cv, int N, int K,
                                          int bx, int by,
                                          unsigned short (*As)[128 * 32],
                                          unsigned short (*Bs)[128 * 32]) {
  const int tid  = threadIdx.x;
  const int wave = tid >> 6, lane = tid & 63;
  const int wm = wave >> 1, wn = wave & 1;
  const int quad = lane >> 4, l15 = lane & 15;
  const int row0 = by * 128;
  const int col0 = bx * 128;
  const int srow = lane >> 2;
  const int scol = (lane & 3) * 8;

  f4v acc[4][4] = {};

#define G_STAGE(KI, BI)                                                         \
  {                                                                             \
    _Pragma("unroll")                                                           \
    for (int cc = 0; cc < 2; cc++) {                                            \
      int c = wave + cc * 4;                                                    \
      gl_lds16(A + (size_t)(row0 + c * 16 + srow) * K + (KI) * 32 + scol,       \
               &As[BI][c * 512]);                                               \
      gl_lds16(B + (size_t)(col0 + c * 16 + srow) * K + (KI) * 32 + scol,       \
               &Bs[BI][c * 512]);                                               \
    }                                                                           \
  }

  const int nk = K >> 5;
  G_STAGE(0, 0);
  __syncthreads();

  for (int ki = 0; ki < nk; ki++) {
    const int cur = ki & 1;
    if (ki + 1 < nk) G_STAGE(ki + 1, 1 - cur);

    s8v af[4], bf[4];
#pragma unroll
    for (int i = 0; i < 4; i++)
      af[i] = *(const s8v*)&As[cur][(wm * 64 + i * 16 + l15) * 32 + quad * 8];
#pragma unroll
    for (int j = 0; j < 4; j++)
      bf[j] = *(const s8v*)&Bs[cur][(wn * 64 + j * 16 + l15) * 32 + quad * 8];
#pragma unroll
    for (int i = 0; i < 4; i++)
#pragma unroll
      for (int j = 0; j < 4; j++)
        acc[i][j] = __builtin_amdgcn_mfma_f32_16x16x32_bf16(af[i], bf[j],
                                                            acc[i][j], 0, 0, 0);
    __syncthreads();
  }
#undef G_STAGE

#pragma unroll
  for (int i = 0; i < 4; i++) {
#pragma unroll
    for (int j = 0; j < 4; j++) {
      int r = row0 + wm * 64 + i * 16 + quad * 4;
      int c = col0 + wn * 64 + j * 16 + l15;
#pragma unroll
      for (int reg = 0; reg < 4; reg++) {
        float v = acc[i][j][reg];
        if constexpr (OUT_BF16)
          ((unsigned short*)Cv)[(size_t)(r + reg) * N + c] = f2bf(v);
        else
          ((float*)Cv)[(size_t)(r + reg) * N + c] = v;
      }
    }
  }
}

// Q + K + V projections in ONE dispatch (1280 blocks, all 128x128 tiles).
__global__ __launch_bounds__(256, 4)
void proj_fused(const unsigned short* __restrict__ qc, const unsigned short* __restrict__ kc,
                const unsigned short* __restrict__ vc, const unsigned short* __restrict__ wqc,
                const unsigned short* __restrict__ wkc, const unsigned short* __restrict__ wvc,
                unsigned short* __restrict__ qp, unsigned short* __restrict__ kp,
                unsigned short* __restrict__ vpt) {
  __shared__ unsigned short As[2][128 * 32];
  __shared__ unsigned short Bs[2][128 * 32];
  int bid = blockIdx.x;
  if (bid < 256) {
    gemm_body<true>(qc, wqc, qp, HID, HID, bid & 7, bid >> 3, As, Bs);
  } else if (bid < 768) {
    int l = bid - 256;
    gemm_body<true>(kc, wkc, kp, HID, HID, l & 7, l >> 3, As, Bs);
  } else {
    int l = bid - 768;
    int b = l >> 8, r = l & 255;
    gemm_body<true>(wvc, vc + (size_t)b * KVL * HID,
                    vpt + (size_t)b * HID * KVL, KVL, HID, r & 31, r >> 5, As, Bs);
  }
}

__global__ __launch_bounds__(256, 4)
void o_gemm(const unsigned short* __restrict__ ao, const unsigned short* __restrict__ woc,
            float* __restrict__ out) {
  __shared__ unsigned short As[2][128 * 32];
  __shared__ unsigned short Bs[2][128 * 32];
  int bid = blockIdx.x;
  gemm_body<false>(ao, woc, out, HID, HID, bid & 7, bid >> 3, As, Bs);
}

// ---------------------------------------------------------------------------
// gemm_conv (fallback for small ws): convert-on-stage GEMM, padded LDS.
// ---------------------------------------------------------------------------
#define LDSK 40

template <typename T>
__device__ __forceinline__ void stage_tile(unsigned short* dst, const T* src,
                                           int ld, int tid, float sc) {
#pragma unroll
  for (int rep = 0; rep < 2; rep++) {
    int s = rep * 256 + tid;
    int row = s >> 2;
    int cs  = (s & 3) * 8;
    const T* p = src + (size_t)row * ld + cs;
    s8v val;
    if constexpr (sizeof(T) == 4) {
      float4 f0 = *(const float4*)p;
      float4 f1 = *(const float4*)(p + 4);
      union { s8v v; unsigned short h[8]; } u;
      u.h[0] = f2bf(f0.x * sc); u.h[1] = f2bf(f0.y * sc);
      u.h[2] = f2bf(f0.z * sc); u.h[3] = f2bf(f0.w * sc);
      u.h[4] = f2bf(f1.x * sc); u.h[5] = f2bf(f1.y * sc);
      u.h[6] = f2bf(f1.z * sc); u.h[7] = f2bf(f1.w * sc);
      val = u.v;
    } else {
      val = *(const s8v*)p;
    }
    *(s8v*)&dst[row * LDSK + cs] = val;
  }
}

template <typename TA, typename TB, bool OUT_BF16>
__global__ __launch_bounds__(256)
void gemm_conv(const TA* __restrict__ A, const TB* __restrict__ B,
               void* __restrict__ Cv, int M, int N, int K, float bscale,
               long long bz, long long cz) {
  __shared__ unsigned short As[128 * LDSK];
  __shared__ unsigned short Bs[128 * LDSK];
  const TB* Bp = B + (size_t)blockIdx.z * (size_t)bz;
  const int tid  = threadIdx.x;
  const int wave = tid >> 6, lane = tid & 63;
  const int wm = wave >> 1, wn = wave & 1;
  const int quad = lane >> 4, l15 = lane & 15;
  const int row0 = blockIdx.y * 128;
  const int col0 = blockIdx.x * 128;

  f4v acc[4][4] = {};

  for (int k0 = 0; k0 < K; k0 += 32) {
    __syncthreads();
    stage_tile(As, A + (size_t)row0 * K + k0, K, tid, 1.0f);
    stage_tile(Bs, Bp + (size_t)col0 * K + k0, K, tid, bscale);
    __syncthreads();

    s8v af[4], bf[4];
#pragma unroll
    for (int i = 0; i < 4; i++)
      af[i] = *(const s8v*)&As[(wm * 64 + i * 16 + l15) * LDSK + quad * 8];
#pragma unroll
    for (int j = 0; j < 4; j++)
      bf[j] = *(const s8v*)&Bs[(wn * 64 + j * 16 + l15) * LDSK + quad * 8];
#pragma unroll
    for (int i = 0; i < 4; i++)
#pragma unroll
      for (int j = 0; j < 4; j++)
        acc[i][j] = __builtin_amdgcn_mfma_f32_16x16x32_bf16(af[i], bf[j],
                                                            acc[i][j], 0, 0, 0);
  }

  char* Cp = (char*)Cv + (size_t)blockIdx.z * (size_t)cz * (OUT_BF16 ? 2 : 4);
#pragma unroll
  for (int i = 0; i < 4; i++) {
#pragma unroll
    for (int j = 0; j < 4; j++) {
      int r = row0 + wm * 64 + i * 16 + quad * 4;
      int c = col0 + wn * 64 + j * 16 + l15;
#pragma unroll
      for (int reg = 0; reg < 4; reg++) {
        float v = acc[i][j][reg];
        if constexpr (OUT_BF16)
          ((unsigned short*)Cp)[(size_t)(r + reg) * N + c] = f2bf(v);
        else
          ((float*)Cp)[(size_t)(r + reg) * N + c] = v;
      }
    }
  }
}

// ---------------------------------------------------------------------------
// attn9: S^T flash attention, 32x32 MFMA, LANE-LOCAL softmax (zero cross-lane
//  P repack; r4's plswap path cost 32 ds_bpermute + 32 cndmask per tile/wave).
//  Key fact: C/D regs e[4s..4s+3] are kv-contiguous (kv = 8s+4hi+j), so the
//  PV A-frag is built lane-locally IF the V B-frag supplies kv {8s+4hi..+3}
//  and {32+8s+4hi..+3} for slot groups j=0..3 / j=4..7. With the XOR chunk
//  swizzle those two b64 groups live at LDS short-offsets o0 and o0^32.
//  Slot-pairing symmetry (A slot (j,hi) multiplies B slot (j,hi)) is exactly
//  what r4's passing kernel verified.
//  LDS ops/wave/tile: 8 b128 (K) + 16 b64 (V). No LDS-pipe softmax ops.
//  Proven attn6-style dbuf sync (__syncthreads per tile). LDS = 32 KB.
// ---------------------------------------------------------------------------
template <bool SPLIT>
__global__ __launch_bounds__(256, 2)
void attn9(const unsigned short* __restrict__ qp,
           const unsigned short* __restrict__ kp,
           const unsigned short* __restrict__ vpt,
           unsigned short* __restrict__ po,   // SPLIT: bf16 [2][NB*QL][HID]
           float* __restrict__ pl,            // SPLIT: f32 [2][NB*NH][QL]
           unsigned short* __restrict__ ao) { // !SPLIT: bf16 [NB*QL][HID]
  __shared__ unsigned short Ks[2][64 * 64];
  __shared__ unsigned short Vt[2][64 * 64];

  const int bid  = blockIdx.x;
  const int qb   = bid & 7;            // QL/256 = 8 q-blocks
  const int h    = (bid >> 3) & 15;
  const int b    = (bid >> 7) & 1;
  const int half = SPLIT ? (bid >> 8) : 0;
  const int tid  = threadIdx.x;
  const int wave = tid >> 6, lane = tid & 63;
  const int l31  = lane & 31, hi = lane >> 5;
  const int q0   = qb * 256 + wave * 64;
  const int kvoff = half * (KVL / 2);
  const int NT   = SPLIT ? (KVL / 128) : (KVL / 64);

  const unsigned short* kbase = kp + (size_t)b * KVL * HID + h * HD + (size_t)kvoff * HID;
  const unsigned short* vbase = vpt + (size_t)(b * NH + h) * HD * KVL + kvoff;

  // DMA staging coords: instr i in {0,1}: LDS chunk p = (i*4+wave)*64 + lane.
  // Global source column pre-swizzled so linear-LDS chunk j of row r holds
  // global chunk j^(r&7); reads use xc = (c ^ (r&7)).
  int prow[2], pcol[2], pbase[2];
#pragma unroll
  for (int i = 0; i < 2; i++) {
    int p = (i * 4 + wave) * 64 + lane;
    prow[i]  = p >> 3;
    pcol[i]  = ((p & 7) ^ (prow[i] & 7)) * 8;
    pbase[i] = (i * 4 + wave) * 512;
  }

  // Q fragments: B-operand of S^T (col=q=nt*32+l31, k=d=ks*16+hi*8+j)
  s8v qf[2][4];
#pragma unroll
  for (int nt = 0; nt < 2; nt++) {
    const unsigned short* qrow = qp + (size_t)(b * QL + q0 + nt * 32 + l31) * HID + h * HD;
#pragma unroll
    for (int ks = 0; ks < 4; ks++)
      qf[nt][ks] = *(const s8v*)(qrow + ks * 16 + hi * 8);
  }

  float lrun[2] = {0.f, 0.f};
  f16x oacc[2][2] = {};   // [nt][dt]: col=d=dt*32+l31, row=q=(r&3)+8*(r>>2)+4*hi

#define STAGE_KV(KT, BI)                                                        \
  {                                                                             \
    const unsigned short* kb = kbase + (size_t)((KT) * 64) * HID;               \
    const unsigned short* vb = vbase + (KT) * 64;                               \
    _Pragma("unroll")                                                           \
    for (int i = 0; i < 2; i++) {                                               \
      gl_lds16(kb + (size_t)prow[i] * HID + pcol[i], &Ks[BI][pbase[i]]);        \
      gl_lds16(vb + (size_t)prow[i] * KVL + pcol[i], &Vt[BI][pbase[i]]);        \
    }                                                                           \
  }

  STAGE_KV(0, 0);
  __syncthreads();

  for (int kt = 0; kt < NT; kt++) {
    const int cur = kt & 1;
    if (kt + 1 < NT) STAGE_KV(kt + 1, 1 - cur);

    // ---- S^T = K.Q^T (A = K-frag: row=kv, B = Q-frag: col=q) ----
    f16x sacc[2][2] = {};   // [mt][nt]
    __builtin_amdgcn_s_setprio(1);
#pragma unroll
    for (int ks = 0; ks < 4; ks++)
#pragma unroll
      for (int mt = 0; mt < 2; mt++) {
        int row = mt * 32 + l31;
        int xc  = ((ks * 2 + hi) ^ (row & 7)) * 8;
        s8v kf = *(const s8v*)&Ks[cur][row * 64 + xc];
#pragma unroll
        for (int nt = 0; nt < 2; nt++)
          sacc[mt][nt] = __builtin_amdgcn_mfma_f32_32x32x16_bf16(kf, qf[nt][ks],
                                                                 sacc[mt][nt], 0, 0, 0);
      }
    __builtin_amdgcn_s_setprio(0);

    // ---- softmax (exp2-domain, fixed shift), fully lane-local ----
    // Lane holds P[q=nt*32+l31][kv = mt*32 + (r&3)+8*(r>>2)+4*hi].
    // Regs r=4s..4s+3 are kv-contiguous: kv = 8s+4hi+(r&3) (+32 for mt=1).
    // PV A-frag for MFMA s: words {0,1} <- e(mt0)[4s..4s+3],
    //                       words {2,3} <- e(mt1)[4s..4s+3]. No cross-lane.
    unsigned paw[2][4][4];  // [nt][s][word]
#pragma unroll
    for (int nt = 0; nt < 2; nt++) {
      float rs = 0.f;
#pragma unroll
      for (int mt = 0; mt < 2; mt++) {
        float e[16];
#pragma unroll
        for (int r = 0; r < 16; r++) e[r] = fexp2(sacc[mt][nt][r]);
        rs += ((((e[0] + e[1]) + (e[2] + e[3])) + ((e[4] + e[5]) + (e[6] + e[7])))
             + (((e[8] + e[9]) + (e[10] + e[11])) + ((e[12] + e[13]) + (e[14] + e[15]))));
#pragma unroll
        for (int s = 0; s < 4; s++) {
          paw[nt][s][2 * mt]     = packbf(e[4 * s],     e[4 * s + 1]);
          paw[nt][s][2 * mt + 1] = packbf(e[4 * s + 2], e[4 * s + 3]);
        }
      }
      rs += __shfl_xor(rs, 32, 64);
      lrun[nt] += rs;
    }

    // ---- O += P.V (A = P-frag lane-local, B = V^T two-b64 frag) ----
    __builtin_amdgcn_s_setprio(1);
#pragma unroll
    for (int s = 0; s < 4; s++)
#pragma unroll
      for (int dt = 0; dt < 2; dt++) {
        int row = dt * 32 + l31;
        // kv = 8s+4hi..+3 at chunk s^(row&7); kv+32 at chunk (s^4)^(row&7)
        int o0  = row * 64 + ((s ^ (row & 7)) * 8) + hi * 4;
        union { s4v h[2]; s8v v; } uv;
        uv.h[0] = *(const s4v*)&Vt[cur][o0];
        uv.h[1] = *(const s4v*)&Vt[cur][o0 ^ 32];
#pragma unroll
        for (int nt = 0; nt < 2; nt++) {
          union { unsigned w[4]; s8v v; } up;
          up.w[0] = paw[nt][s][0]; up.w[1] = paw[nt][s][1];
          up.w[2] = paw[nt][s][2]; up.w[3] = paw[nt][s][3];
          oacc[nt][dt] = __builtin_amdgcn_mfma_f32_32x32x16_bf16(up.v, uv.v,
                                                                 oacc[nt][dt], 0, 0, 0);
        }
      }
    __builtin_amdgcn_s_setprio(0);

    __syncthreads();
  }
#undef STAGE_KV

  if constexpr (SPLIT) {
    // unnormalized partials: O (bf16) + l (f32)
    unsigned short* pob = po + (size_t)half * NB * QL * HID;
#pragma unroll
    for (int nt = 0; nt < 2; nt++) {
#pragma unroll
      for (int dt = 0; dt < 2; dt++)
#pragma unroll
        for (int r = 0; r < 16; r++) {
          int qq = q0 + nt * 32 + (r & 3) + 8 * (r >> 2) + 4 * hi;
          int cc = h * HD + dt * 32 + l31;
          pob[(size_t)(b * QL + qq) * HID + cc] = f2bf(oacc[nt][dt][r]);
        }
      if (hi == 0)
        pl[(size_t)half * NB * NH * QL + (b * NH + h) * QL + q0 + nt * 32 + l31] = lrun[nt];
    }
  } else {
#pragma unroll
    for (int nt = 0; nt < 2; nt++) {
      float li = 1.0f / lrun[nt];
#pragma unroll
      for (int dt = 0; dt < 2; dt++)
#pragma unroll
        for (int r = 0; r < 16; r++) {
          int rr = (r & 3) + 8 * (r >> 2) + 4 * hi;
          float lv = __shfl(li, rr, 64);   // lane rr holds 1/l for q=nt*32+rr
          int qq = q0 + nt * 32 + rr;
          int cc = h * HD + dt * 32 + l31;
          ao[(size_t)(b * QL + qq) * HID + cc] = f2bf(oacc[nt][dt][r] * lv);
        }
    }
  }
}

// combine: ao = (po0 + po1) / (l0 + l1).  524288 threads, 8 elems each.
__global__ __launch_bounds__(256)
void combine(const unsigned short* __restrict__ po, const float* __restrict__ pl,
             unsigned short* __restrict__ ao) {
  int t  = blockIdx.x * 256 + threadIdx.x;
  int r  = t >> 7;           // row 0..4095 (b*QL+q)
  int c8 = t & 127;          // 8-col chunk; head h = c8>>3
  int b = r >> 11, q = r & 2047, h = c8 >> 3;
  size_t lidx = (size_t)(b * NH + h) * QL + q;
  float l = pl[lidx] + pl[(size_t)NB * NH * QL + lidx];
  float inv = 1.0f / l;
  size_t off = (size_t)r * HID + c8 * 8;
  s8v a = *(const s8v*)(po + off);
  s8v c = *(const s8v*)(po + (size_t)NB * QL * HID + off);
  union { s8v v8; unsigned short hh[8]; } ua, uc, uo;
  ua.v8 = a; uc.v8 = c;
#pragma unroll
  for (int e = 0; e < 8; e++)
    uo.hh[e] = f2bf((bf2f(ua.hh[e]) + bf2f(uc.hh[e])) * inv);
  *(s8v*)(ao + off) = uo.v8;
}

// ---------------------------------------------------------------------------
// Launch. Primary (ws >= 88 MiB):
//   @0 qc(8)->ao | @8 kc+vc(32)->po | @40 wqc(2)->pl | @42 wkc @44 wvc
//   @46 woc | @48 qp(8) | @56 kp(16) | @72 vpt(16)
// Fallback (48 MiB): gemm_conv chain + attn9<false> direct.
// ---------------------------------------------------------------------------
extern "C" void kernel_launch(void* const* d_in, const int* in_sizes, int n_in,
                              void* d_out, int out_size, void* d_ws, size_t ws_size,
                              hipStream_t stream) {
  const float* q  = (const float*)d_in[0];
  const float* k  = (const float*)d_in[1];
  const float* v  = (const float*)d_in[2];
  const float* Wq = (const float*)d_in[3];
  const float* Wk = (const float*)d_in[4];
  const float* Wv = (const float*)d_in[5];
  const float* Wo = (const float*)d_in[6];
  float* out = (float*)d_out;
  char* ws = (char*)d_ws;
  dim3 blk(256);

  const long long MB = 1024 * 1024;
  if (ws_size >= (size_t)88 * MB) {
    unsigned short* qc  = (unsigned short*)(ws);
    unsigned short* kc  = (unsigned short*)(ws + 8 * MB);
    unsigned short* vc  = (unsigned short*)(ws + 24 * MB);
    unsigned short* wqc = (unsigned short*)(ws + 40 * MB);
    unsigned short* wkc = (unsigned short*)(ws + 42 * MB);
    unsigned short* wvc = (unsigned short*)(ws + 44 * MB);
    unsigned short* woc = (unsigned short*)(ws + 46 * MB);
    unsigned short* qp  = (unsigned short*)(ws + 48 * MB);
    unsigned short* kp  = (unsigned short*)(ws + 56 * MB);
    unsigned short* vpt = (unsigned short*)(ws + 72 * MB);
    unsigned short* ao  = (unsigned short*)(ws);            // aliases qc (dead after proj)
    unsigned short* po  = (unsigned short*)(ws + 8 * MB);   // aliases kc/vc (dead after proj)
    float*          pl  = (float*)(ws + 40 * MB);           // aliases wqc (dead after proj)

    cast_all<<<12288, blk, 0, stream>>>(q, k, v, Wq, Wk, Wv, Wo, (unsigned short*)ws);
    proj_fused<<<1280, blk, 0, stream>>>(qc, kc, vc, wqc, wkc, wvc, qp, kp, vpt);
    attn9<true><<<512, blk, 0, stream>>>(qp, kp, vpt, po, pl, nullptr);
    combine<<<2048, blk, 0, stream>>>(po, pl, ao);
    o_gemm<<<256, blk, 0, stream>>>(ao, woc, out);
  } else {
    unsigned short* qp  = (unsigned short*)(ws);
    unsigned short* kp  = (unsigned short*)(ws + 8 * MB);
    unsigned short* vpt = (unsigned short*)(ws + 24 * MB);
    unsigned short* ao  = (unsigned short*)(ws + 40 * MB);

    gemm_conv<float, float, true><<<dim3(8, 32), blk, 0, stream>>>(q, Wq, qp, NB * QL, HID, HID, QSCALE, 0, 0);
    gemm_conv<float, float, true><<<dim3(8, 64), blk, 0, stream>>>(k, Wk, kp, NB * KVL, HID, HID, 1.0f, 0, 0);
    gemm_conv<float, float, true><<<dim3(32, 8, 2), blk, 0, stream>>>(Wv, v, vpt, HID, KVL, HID, 1.0f,
                                                                      (long long)KVL * HID, (long long)HID * KVL);
    attn9<false><<<256, blk, 0, stream>>>(qp, kp, vpt, nullptr, nullptr, ao);
    gemm_conv<unsigned short, float, false><<<dim3(8, 32), blk, 0, stream>>>(ao, Wo, out, NB * QL, HID, HID, 1.0f, 0, 0);
  }
}

// Round 7
// 305.961 us; speedup vs baseline: 1.0590x; 1.0072x over previous
//
#include <hip/hip_runtime.h>

// Problem constants (reference: B=2, QL=2048, KVL=4096, HIDDEN=1024, NH=16, D=64)
#define HID   1024
#define NH    16
#define HD    64
#define QL    2048
#define KVL   4096
#define NB    2
// SCALE=0.125 and log2(e) folded into Wq at cast time; softmax uses exp2.
#define QSCALE 0.180336880111120426f

typedef short s8v  __attribute__((ext_vector_type(8)));  // 8 x bf16 bits (4 VGPRs)
typedef short s4v  __attribute__((ext_vector_type(4)));  // 4 x bf16 bits (b64)
typedef float f4v  __attribute__((ext_vector_type(4)));  // 16x16 MFMA accumulator
typedef float f16x __attribute__((ext_vector_type(16))); // 32x32 MFMA accumulator

__device__ __forceinline__ unsigned short f2bf(float f) {
  unsigned int u = __builtin_bit_cast(unsigned int, f);
  u += 0x7FFFu + ((u >> 16) & 1u);
  return (unsigned short)(u >> 16);
}
__device__ __forceinline__ float bf2f(unsigned short h) {
  unsigned int u = ((unsigned int)h) << 16;
  return __builtin_bit_cast(float, u);
}
__device__ __forceinline__ float fexp2(float x) {
#if __has_builtin(__builtin_amdgcn_exp2f)
  return __builtin_amdgcn_exp2f(x);
#else
  return exp2f(x);
#endif
}

// Pack two f32 -> one u32 of 2 bf16 by TRUNCATION (2 bit-ops, no semantic
// unknowns). P is all-positive; the small downward bias appears identically
// in O = P.V and l = P.1 (both via MFMA on the same packed P) and cancels
// in O/l. attn6 passed with truncated P against an f32-exact denominator.
// NOTE: v_cvt_pk_bf16_f32 inline asm is BANNED: r3 (S0=lo) FAIL 9.9e-3 and
// r6 (S0=hi) FAIL 2.05e-2 prove neither operand order gives the assumed
// pack semantics on gfx950; m240 says it's slower than scalar casts anyway.
__device__ __forceinline__ unsigned truncpk(float lo, float hi) {
  unsigned ulo = __builtin_bit_cast(unsigned, lo);
  unsigned uhi = __builtin_bit_cast(unsigned, hi);
  return (ulo >> 16) | (uhi & 0xFFFF0000u);
}

// ---------------------------------------------------------------------------
// cast_all: fp32 -> bf16 for all 7 tensors into one contiguous ws region.
// ---------------------------------------------------------------------------
__global__ __launch_bounds__(256)
void cast_all(const float* __restrict__ q, const float* __restrict__ k,
              const float* __restrict__ v, const float* __restrict__ wq,
              const float* __restrict__ wk, const float* __restrict__ wv,
              const float* __restrict__ wo, unsigned short* __restrict__ dst) {
  size_t c = (size_t)blockIdx.x * 256 + threadIdx.x;
  const float* src; size_t lc; float sc = 1.0f;
  if (c < 524288)       { src = q;  lc = c; }
  else if (c < 1572864) { src = k;  lc = c - 524288; }
  else if (c < 2621440) { src = v;  lc = c - 1572864; }
  else if (c < 2752512) { src = wq; lc = c - 2621440; sc = QSCALE; }
  else if (c < 2883584) { src = wk; lc = c - 2752512; }
  else if (c < 3014656) { src = wv; lc = c - 2883584; }
  else                  { src = wo; lc = c - 3014656; }
  const float4* p = (const float4*)(src + lc * 8);
  float4 a = p[0], b = p[1];
  union { s8v v8; unsigned short h[8]; } u;
  u.h[0] = f2bf(a.x * sc); u.h[1] = f2bf(a.y * sc);
  u.h[2] = f2bf(a.z * sc); u.h[3] = f2bf(a.w * sc);
  u.h[4] = f2bf(b.x * sc); u.h[5] = f2bf(b.y * sc);
  u.h[6] = f2bf(b.z * sc); u.h[7] = f2bf(b.w * sc);
  *(s8v*)(dst + c * 8) = u.v8;
}

// ---------------------------------------------------------------------------
// DMA helper
// ---------------------------------------------------------------------------
typedef const __attribute__((address_space(1))) unsigned int* gas_t;
typedef __attribute__((address_space(3))) unsigned int*       las_t;

__device__ __forceinline__ void gl_lds16(const unsigned short* g, unsigned short* l) {
  __builtin_amdgcn_global_load_lds((gas_t)(const void*)g, (las_t)(void*)l, 16, 0, 0);
}

// ---------------------------------------------------------------------------
// GEMM body, dbuf DMA staging. Per-iter barrier drains vmcnt(0) (structural);
// mitigation = 4 blocks/CU so 4 barrier-groups overlap their drains.
// ---------------------------------------------------------------------------
template <bool OUT_BF16>
__device__ __forceinline__ void gemm_body(const unsigned short* __restrict__ A,
                                          const unsigned short* __restrict__ B,
                                          void* __restrict__ Cv, int N, int K,
                                          int bx, int by,
                                          unsigned short (*As)[128 * 32],
                                          unsigned short (*Bs)[128 * 32]) {
  const int tid  = threadIdx.x;
  const int wave = tid >> 6, lane = tid & 63;
  const int wm = wave >> 1, wn = wave & 1;
  const int quad = lane >> 4, l15 = lane & 15;
  const int row0 = by * 128;
  const int col0 = bx * 128;
  const int srow = lane >> 2;
  const int scol = (lane & 3) * 8;

  f4v acc[4][4] = {};

#define G_STAGE(KI, BI)                                                         \
  {                                                                             \
    _Pragma("unroll")                                                           \
    for (int cc = 0; cc < 2; cc++) {                                            \
      int c = wave + cc * 4;                                                    \
      gl_lds16(A + (size_t)(row0 + c * 16 + srow) * K + (KI) * 32 + scol,       \
               &As[BI][c * 512]);                                               \
      gl_lds16(B + (size_t)(col0 + c * 16 + srow) * K + (KI) * 32 + scol,       \
               &Bs[BI][c * 512]);                                               \
    }                                                                           \
  }

  const int nk = K >> 5;
  G_STAGE(0, 0);
  __syncthreads();

  for (int ki = 0; ki < nk; ki++) {
    const int cur = ki & 1;
    if (ki + 1 < nk) G_STAGE(ki + 1, 1 - cur);

    s8v af[4], bf[4];
#pragma unroll
    for (int i = 0; i < 4; i++)
      af[i] = *(const s8v*)&As[cur][(wm * 64 + i * 16 + l15) * 32 + quad * 8];
#pragma unroll
    for (int j = 0; j < 4; j++)
      bf[j] = *(const s8v*)&Bs[cur][(wn * 64 + j * 16 + l15) * 32 + quad * 8];
#pragma unroll
    for (int i = 0; i < 4; i++)
#pragma unroll
      for (int j = 0; j < 4; j++)
        acc[i][j] = __builtin_amdgcn_mfma_f32_16x16x32_bf16(af[i], bf[j],
                                                            acc[i][j], 0, 0, 0);
    __syncthreads();
  }
#undef G_STAGE

#pragma unroll
  for (int i = 0; i < 4; i++) {
#pragma unroll
    for (int j = 0; j < 4; j++) {
      int r = row0 + wm * 64 + i * 16 + quad * 4;
      int c = col0 + wn * 64 + j * 16 + l15;
#pragma unroll
      for (int reg = 0; reg < 4; reg++) {
        float v = acc[i][j][reg];
        if constexpr (OUT_BF16)
          ((unsigned short*)Cv)[(size_t)(r + reg) * N + c] = f2bf(v);
        else
          ((float*)Cv)[(size_t)(r + reg) * N + c] = v;
      }
    }
  }
}

// Q + K + V projections in ONE dispatch (1280 blocks, all 128x128 tiles).
__global__ __launch_bounds__(256, 4)
void proj_fused(const unsigned short* __restrict__ qc, const unsigned short* __restrict__ kc,
                const unsigned short* __restrict__ vc, const unsigned short* __restrict__ wqc,
                const unsigned short* __restrict__ wkc, const unsigned short* __restrict__ wvc,
                unsigned short* __restrict__ qp, unsigned short* __restrict__ kp,
                unsigned short* __restrict__ vpt) {
  __shared__ unsigned short As[2][128 * 32];
  __shared__ unsigned short Bs[2][128 * 32];
  int bid = blockIdx.x;
  if (bid < 256) {
    gemm_body<true>(qc, wqc, qp, HID, HID, bid & 7, bid >> 3, As, Bs);
  } else if (bid < 768) {
    int l = bid - 256;
    gemm_body<true>(kc, wkc, kp, HID, HID, l & 7, l >> 3, As, Bs);
  } else {
    int l = bid - 768;
    int b = l >> 8, r = l & 255;
    gemm_body<true>(wvc, vc + (size_t)b * KVL * HID,
                    vpt + (size_t)b * HID * KVL, KVL, HID, r & 31, r >> 5, As, Bs);
  }
}

__global__ __launch_bounds__(256, 4)
void o_gemm(const unsigned short* __restrict__ ao, const unsigned short* __restrict__ woc,
            float* __restrict__ out) {
  __shared__ unsigned short As[2][128 * 32];
  __shared__ unsigned short Bs[2][128 * 32];
  int bid = blockIdx.x;
  gemm_body<false>(ao, woc, out, HID, HID, bid & 7, bid >> 3, As, Bs);
}

// ---------------------------------------------------------------------------
// gemm_conv (fallback for small ws): convert-on-stage GEMM, padded LDS.
// ---------------------------------------------------------------------------
#define LDSK 40

template <typename T>
__device__ __forceinline__ void stage_tile(unsigned short* dst, const T* src,
                                           int ld, int tid, float sc) {
#pragma unroll
  for (int rep = 0; rep < 2; rep++) {
    int s = rep * 256 + tid;
    int row = s >> 2;
    int cs  = (s & 3) * 8;
    const T* p = src + (size_t)row * ld + cs;
    s8v val;
    if constexpr (sizeof(T) == 4) {
      float4 f0 = *(const float4*)p;
      float4 f1 = *(const float4*)(p + 4);
      union { s8v v; unsigned short h[8]; } u;
      u.h[0] = f2bf(f0.x * sc); u.h[1] = f2bf(f0.y * sc);
      u.h[2] = f2bf(f0.z * sc); u.h[3] = f2bf(f0.w * sc);
      u.h[4] = f2bf(f1.x * sc); u.h[5] = f2bf(f1.y * sc);
      u.h[6] = f2bf(f1.z * sc); u.h[7] = f2bf(f1.w * sc);
      val = u.v;
    } else {
      val = *(const s8v*)p;
    }
    *(s8v*)&dst[row * LDSK + cs] = val;
  }
}

template <typename TA, typename TB, bool OUT_BF16>
__global__ __launch_bounds__(256)
void gemm_conv(const TA* __restrict__ A, const TB* __restrict__ B,
               void* __restrict__ Cv, int M, int N, int K, float bscale,
               long long bz, long long cz) {
  __shared__ unsigned short As[128 * LDSK];
  __shared__ unsigned short Bs[128 * LDSK];
  const TB* Bp = B + (size_t)blockIdx.z * (size_t)bz;
  const int tid  = threadIdx.x;
  const int wave = tid >> 6, lane = tid & 63;
  const int wm = wave >> 1, wn = wave & 1;
  const int quad = lane >> 4, l15 = lane & 15;
  const int row0 = blockIdx.y * 128;
  const int col0 = blockIdx.x * 128;

  f4v acc[4][4] = {};

  for (int k0 = 0; k0 < K; k0 += 32) {
    __syncthreads();
    stage_tile(As, A + (size_t)row0 * K + k0, K, tid, 1.0f);
    stage_tile(Bs, Bp + (size_t)col0 * K + k0, K, tid, bscale);
    __syncthreads();

    s8v af[4], bf[4];
#pragma unroll
    for (int i = 0; i < 4; i++)
      af[i] = *(const s8v*)&As[(wm * 64 + i * 16 + l15) * LDSK + quad * 8];
#pragma unroll
    for (int j = 0; j < 4; j++)
      bf[j] = *(const s8v*)&Bs[(wn * 64 + j * 16 + l15) * LDSK + quad * 8];
#pragma unroll
    for (int i = 0; i < 4; i++)
#pragma unroll
      for (int j = 0; j < 4; j++)
        acc[i][j] = __builtin_amdgcn_mfma_f32_16x16x32_bf16(af[i], bf[j],
                                                            acc[i][j], 0, 0, 0);
  }

  char* Cp = (char*)Cv + (size_t)blockIdx.z * (size_t)cz * (OUT_BF16 ? 2 : 4);
#pragma unroll
  for (int i = 0; i < 4; i++) {
#pragma unroll
    for (int j = 0; j < 4; j++) {
      int r = row0 + wm * 64 + i * 16 + quad * 4;
      int c = col0 + wn * 64 + j * 16 + l15;
#pragma unroll
      for (int reg = 0; reg < 4; reg++) {
        float v = acc[i][j][reg];
        if constexpr (OUT_BF16)
          ((unsigned short*)Cp)[(size_t)(r + reg) * N + c] = f2bf(v);
        else
          ((float*)Cp)[(size_t)(r + reg) * N + c] = v;
      }
    }
  }
}

// ---------------------------------------------------------------------------
// attn11: r5's attn9 (95.7us PASS) + ones-MFMA row-sum (lacc), ISOLATED:
//  - P pack by truncation (bit-ops only; cvtpk asm banned per r3/r6 evidence)
//  - l = P.1 via 8 extra MFMAs/tile into lacc[nt]; D-layout row-aligned with
//    oacc -> zero shuffles in loop AND epilogue; removes ~62 VALU adds +
//    2 shfl_xor (LDS pipe) per tile/wave. Num & denom share the same rounded
//    P -> truncation bias cancels in O/l.
//  Structure (32x32 MFMA, lane-local P, XOR-swizzled K/V LDS, dbuf
//  __syncthreads) unchanged from the r5 PASS. LDS = 32 KB.
// ---------------------------------------------------------------------------
template <bool SPLIT>
__global__ __launch_bounds__(256, 2)
void attn11(const unsigned short* __restrict__ qp,
            const unsigned short* __restrict__ kp,
            const unsigned short* __restrict__ vpt,
            unsigned short* __restrict__ po,   // SPLIT: bf16 [2][NB*QL][HID]
            float* __restrict__ pl,            // SPLIT: f32 [2][NB*NH][QL]
            unsigned short* __restrict__ ao) { // !SPLIT: bf16 [NB*QL][HID]
  __shared__ unsigned short Ks[2][64 * 64];
  __shared__ unsigned short Vt[2][64 * 64];

  const int bid  = blockIdx.x;
  const int qb   = bid & 7;            // QL/256 = 8 q-blocks
  const int h    = (bid >> 3) & 15;
  const int b    = (bid >> 7) & 1;
  const int half = SPLIT ? (bid >> 8) : 0;
  const int tid  = threadIdx.x;
  const int wave = tid >> 6, lane = tid & 63;
  const int l31  = lane & 31, hi = lane >> 5;
  const int q0   = qb * 256 + wave * 64;
  const int kvoff = half * (KVL / 2);
  const int NT   = SPLIT ? (KVL / 128) : (KVL / 64);

  const unsigned short* kbase = kp + (size_t)b * KVL * HID + h * HD + (size_t)kvoff * HID;
  const unsigned short* vbase = vpt + (size_t)(b * NH + h) * HD * KVL + kvoff;

  // DMA staging coords: instr i in {0,1}: LDS chunk p = (i*4+wave)*64 + lane.
  // Global source column pre-swizzled so linear-LDS chunk j of row r holds
  // global chunk j^(r&7); reads use xc = (c ^ (r&7)).
  int prow[2], pcol[2], pbase[2];
#pragma unroll
  for (int i = 0; i < 2; i++) {
    int p = (i * 4 + wave) * 64 + lane;
    prow[i]  = p >> 3;
    pcol[i]  = ((p & 7) ^ (prow[i] & 7)) * 8;
    pbase[i] = (i * 4 + wave) * 512;
  }

  // Q fragments: B-operand of S^T (col=q=nt*32+l31, k=d=ks*16+hi*8+j)
  s8v qf[2][4];
#pragma unroll
  for (int nt = 0; nt < 2; nt++) {
    const unsigned short* qrow = qp + (size_t)(b * QL + q0 + nt * 32 + l31) * HID + h * HD;
#pragma unroll
    for (int ks = 0; ks < 4; ks++)
      qf[nt][ks] = *(const s8v*)(qrow + ks * 16 + hi * 8);
  }

  // all-ones bf16 B-fragment for the l-sum MFMA (layout-irrelevant: every
  // slot = 1.0, so D[q][*] = sum_kv P[q][kv] regardless of k-mapping)
  union { unsigned w[4]; s8v v; } uones;
#pragma unroll
  for (int i = 0; i < 4; i++) uones.w[i] = 0x3F803F80u;

  f16x oacc[2][2] = {};   // [nt][dt]: col=d=dt*32+l31, row=q=(r&3)+8*(r>>2)+4*hi
  f16x lacc[2]    = {};   // [nt]: same row formula, all cols equal = sum_kv P

#define STAGE_KV(KT, BI)                                                        \
  {                                                                             \
    const unsigned short* kb = kbase + (size_t)((KT) * 64) * HID;               \
    const unsigned short* vb = vbase + (KT) * 64;                               \
    _Pragma("unroll")                                                           \
    for (int i = 0; i < 2; i++) {                                               \
      gl_lds16(kb + (size_t)prow[i] * HID + pcol[i], &Ks[BI][pbase[i]]);        \
      gl_lds16(vb + (size_t)prow[i] * KVL + pcol[i], &Vt[BI][pbase[i]]);        \
    }                                                                           \
  }

  STAGE_KV(0, 0);
  __syncthreads();

  for (int kt = 0; kt < NT; kt++) {
    const int cur = kt & 1;
    if (kt + 1 < NT) STAGE_KV(kt + 1, 1 - cur);

    // ---- S^T = K.Q^T (A = K-frag: row=kv, B = Q-frag: col=q) ----
    f16x sacc[2][2] = {};   // [mt][nt]
    __builtin_amdgcn_s_setprio(1);
#pragma unroll
    for (int ks = 0; ks < 4; ks++)
#pragma unroll
      for (int mt = 0; mt < 2; mt++) {
        int row = mt * 32 + l31;
        int xc  = ((ks * 2 + hi) ^ (row & 7)) * 8;
        s8v kf = *(const s8v*)&Ks[cur][row * 64 + xc];
#pragma unroll
        for (int nt = 0; nt < 2; nt++)
          sacc[mt][nt] = __builtin_amdgcn_mfma_f32_32x32x16_bf16(kf, qf[nt][ks],
                                                                 sacc[mt][nt], 0, 0, 0);
      }
    __builtin_amdgcn_s_setprio(0);

    // ---- softmax (exp2-domain, fixed shift), fully lane-local ----
    // Lane holds P[q=nt*32+l31][kv = mt*32 + (r&3)+8*(r>>2)+4*hi].
    // Regs r=4s..4s+3 are kv-contiguous: kv = 8s+4hi+(r&3) (+32 for mt=1).
    // PV A-frag for MFMA s: words {0,1} <- e(mt0)[4s..4s+3],
    //                       words {2,3} <- e(mt1)[4s..4s+3]. No cross-lane.
    unsigned paw[2][4][4];  // [nt][s][word]
#pragma unroll
    for (int nt = 0; nt < 2; nt++) {
#pragma unroll
      for (int mt = 0; mt < 2; mt++) {
        float e[16];
#pragma unroll
        for (int r = 0; r < 16; r++) e[r] = fexp2(sacc[mt][nt][r]);
#pragma unroll
        for (int s = 0; s < 4; s++) {
          paw[nt][s][2 * mt]     = truncpk(e[4 * s],     e[4 * s + 1]);
          paw[nt][s][2 * mt + 1] = truncpk(e[4 * s + 2], e[4 * s + 3]);
        }
      }
    }

    // ---- O += P.V, l += P.1 (A = P-frag lane-local) ----
    __builtin_amdgcn_s_setprio(1);
#pragma unroll
    for (int s = 0; s < 4; s++) {
      union { unsigned w[4]; s8v v; } up[2];
#pragma unroll
      for (int nt = 0; nt < 2; nt++) {
        up[nt].w[0] = paw[nt][s][0]; up[nt].w[1] = paw[nt][s][1];
        up[nt].w[2] = paw[nt][s][2]; up[nt].w[3] = paw[nt][s][3];
      }
#pragma unroll
      for (int dt = 0; dt < 2; dt++) {
        int row = dt * 32 + l31;
        // kv = 8s+4hi..+3 at chunk s^(row&7); kv+32 at chunk (s^4)^(row&7)
        int o0  = row * 64 + ((s ^ (row & 7)) * 8) + hi * 4;
        union { s4v hh[2]; s8v v; } uv;
        uv.hh[0] = *(const s4v*)&Vt[cur][o0];
        uv.hh[1] = *(const s4v*)&Vt[cur][o0 ^ 32];
#pragma unroll
        for (int nt = 0; nt < 2; nt++)
          oacc[nt][dt] = __builtin_amdgcn_mfma_f32_32x32x16_bf16(up[nt].v, uv.v,
                                                                 oacc[nt][dt], 0, 0, 0);
      }
#pragma unroll
      for (int nt = 0; nt < 2; nt++)
        lacc[nt] = __builtin_amdgcn_mfma_f32_32x32x16_bf16(up[nt].v, uones.v,
                                                           lacc[nt], 0, 0, 0);
    }
    __builtin_amdgcn_s_setprio(0);

    __syncthreads();
  }
#undef STAGE_KV

  if constexpr (SPLIT) {
    // unnormalized partials: O (bf16) + l (f32)
    unsigned short* pob = po + (size_t)half * NB * QL * HID;
#pragma unroll
    for (int nt = 0; nt < 2; nt++) {
#pragma unroll
      for (int dt = 0; dt < 2; dt++)
#pragma unroll
        for (int r = 0; r < 16; r++) {
          int qq = q0 + nt * 32 + (r & 3) + 8 * (r >> 2) + 4 * hi;
          int cc = h * HD + dt * 32 + l31;
          pob[(size_t)(b * QL + qq) * HID + cc] = f2bf(oacc[nt][dt][r]);
        }
      if (l31 == 0) {
        // lanes 0 (hi=0) and 32 (hi=1) cover disjoint q rows
        float* plb = pl + (size_t)half * NB * NH * QL + (size_t)(b * NH + h) * QL;
#pragma unroll
        for (int r = 0; r < 16; r++)
          plb[q0 + nt * 32 + (r & 3) + 8 * (r >> 2) + 4 * hi] = lacc[nt][r];
      }
    }
  } else {
#pragma unroll
    for (int nt = 0; nt < 2; nt++) {
#pragma unroll
      for (int r = 0; r < 16; r++) {
        float lv = 1.0f / lacc[nt][r];   // row-aligned with oacc: no shuffle
        int qq = q0 + nt * 32 + (r & 3) + 8 * (r >> 2) + 4 * hi;
#pragma unroll
        for (int dt = 0; dt < 2; dt++) {
          int cc = h * HD + dt * 32 + l31;
          ao[(size_t)(b * QL + qq) * HID + cc] = f2bf(oacc[nt][dt][r] * lv);
        }
      }
    }
  }
}

// combine: ao = (po0 + po1) / (l0 + l1).  524288 threads, 8 elems each.
__global__ __launch_bounds__(256)
void combine(const unsigned short* __restrict__ po, const float* __restrict__ pl,
             unsigned short* __restrict__ ao) {
  int t  = blockIdx.x * 256 + threadIdx.x;
  int r  = t >> 7;           // row 0..4095 (b*QL+q)
  int c8 = t & 127;          // 8-col chunk; head h = c8>>3
  int b = r >> 11, q = r & 2047, h = c8 >> 3;
  size_t lidx = (size_t)(b * NH + h) * QL + q;
  float l = pl[lidx] + pl[(size_t)NB * NH * QL + lidx];
  float inv = 1.0f / l;
  size_t off = (size_t)r * HID + c8 * 8;
  s8v a = *(const s8v*)(po + off);
  s8v c = *(const s8v*)(po + (size_t)NB * QL * HID + off);
  union { s8v v8; unsigned short hh[8]; } ua, uc, uo;
  ua.v8 = a; uc.v8 = c;
#pragma unroll
  for (int e = 0; e < 8; e++)
    uo.hh[e] = f2bf((bf2f(ua.hh[e]) + bf2f(uc.hh[e])) * inv);
  *(s8v*)(ao + off) = uo.v8;
}

// ---------------------------------------------------------------------------
// Launch. Primary (ws >= 88 MiB):
//   @0 qc(8)->ao | @8 kc+vc(32)->po | @40 wqc(2)->pl | @42 wkc @44 wvc
//   @46 woc | @48 qp(8) | @56 kp(16) | @72 vpt(16)
// Fallback (48 MiB): gemm_conv chain + attn11<false> direct.
// ---------------------------------------------------------------------------
extern "C" void kernel_launch(void* const* d_in, const int* in_sizes, int n_in,
                              void* d_out, int out_size, void* d_ws, size_t ws_size,
                              hipStream_t stream) {
  const float* q  = (const float*)d_in[0];
  const float* k  = (const float*)d_in[1];
  const float* v  = (const float*)d_in[2];
  const float* Wq = (const float*)d_in[3];
  const float* Wk = (const float*)d_in[4];
  const float* Wv = (const float*)d_in[5];
  const float* Wo = (const float*)d_in[6];
  float* out = (float*)d_out;
  char* ws = (char*)d_ws;
  dim3 blk(256);

  const long long MB = 1024 * 1024;
  if (ws_size >= (size_t)88 * MB) {
    unsigned short* qc  = (unsigned short*)(ws);
    unsigned short* kc  = (unsigned short*)(ws + 8 * MB);
    unsigned short* vc  = (unsigned short*)(ws + 24 * MB);
    unsigned short* wqc = (unsigned short*)(ws + 40 * MB);
    unsigned short* wkc = (unsigned short*)(ws + 42 * MB);
    unsigned short* wvc = (unsigned short*)(ws + 44 * MB);
    unsigned short* woc = (unsigned short*)(ws + 46 * MB);
    unsigned short* qp  = (unsigned short*)(ws + 48 * MB);
    unsigned short* kp  = (unsigned short*)(ws + 56 * MB);
    unsigned short* vpt = (unsigned short*)(ws + 72 * MB);
    unsigned short* ao  = (unsigned short*)(ws);            // aliases qc (dead after proj)
    unsigned short* po  = (unsigned short*)(ws + 8 * MB);   // aliases kc/vc (dead after proj)
    float*          pl  = (float*)(ws + 40 * MB);           // aliases wqc (dead after proj)

    cast_all<<<12288, blk, 0, stream>>>(q, k, v, Wq, Wk, Wv, Wo, (unsigned short*)ws);
    proj_fused<<<1280, blk, 0, stream>>>(qc, kc, vc, wqc, wkc, wvc, qp, kp, vpt);
    attn11<true><<<512, blk, 0, stream>>>(qp, kp, vpt, po, pl, nullptr);
    combine<<<2048, blk, 0, stream>>>(po, pl, ao);
    o_gemm<<<256, blk, 0, stream>>>(ao, woc, out);
  } else {
    unsigned short* qp  = (unsigned short*)(ws);
    unsigned short* kp  = (unsigned short*)(ws + 8 * MB);
    unsigned short* vpt = (unsigned short*)(ws + 24 * MB);
    unsigned short* ao  = (unsigned short*)(ws + 40 * MB);

    gemm_conv<float, float, true><<<dim3(8, 32), blk, 0, stream>>>(q, Wq, qp, NB * QL, HID, HID, QSCALE, 0, 0);
    gemm_conv<float, float, true><<<dim3(8, 64), blk, 0, stream>>>(k, Wk, kp, NB * KVL, HID, HID, 1.0f, 0, 0);
    gemm_conv<float, float, true><<<dim3(32, 8, 2), blk, 0, stream>>>(Wv, v, vpt, HID, KVL, HID, 1.0f,
                                                                      (long long)KVL * HID, (long long)HID * KVL);
    attn11<false><<<256, blk, 0, stream>>>(qp, kp, vpt, nullptr, nullptr, ao);
    gemm_conv<unsigned short, float, false><<<dim3(8, 32), blk, 0, stream>>>(ao, Wo, out, NB * QL, HID, HID, 1.0f, 0, 0);
  }
}